// Round 2
// 667.166 us; speedup vs baseline: 1.2715x; 1.2715x over previous
//
#include <hip/hip_runtime.h>
#include <hip/hip_bf16.h>
#include <math.h>

using bf16 = __hip_bfloat16;
typedef __bf16 bf16x8 __attribute__((ext_vector_type(8)));
typedef __bf16 bf16x4 __attribute__((ext_vector_type(4)));
typedef float floatx4 __attribute__((ext_vector_type(4)));

__device__ __forceinline__ float bf2f(bf16 x) { return __bfloat162float(x); }
__device__ __forceinline__ bf16 f2bf(float x) { return __float2bfloat16(x); }

// flag semantics: flagp[0] == 1 -> external tensors are bf16; 0 -> float32.
__device__ __forceinline__ float loadExt(const void* p, long i, int f32) {
  return f32 ? ((const float*)p)[i] : bf2f(((const bf16*)p)[i]);
}
__device__ __forceinline__ void storeExt(void* p, long i, int f32, float v) {
  if (f32) ((float*)p)[i] = v;
  else     ((bf16*)p)[i] = f2bf(v);
}

// async 16B global->LDS copy (gfx950). LDS dest is wave-uniform base + lane*16.
#define GLOAD16(gp, lp)                                                       \
  __builtin_amdgcn_global_load_lds(                                           \
      (const __attribute__((address_space(1))) void*)(gp),                    \
      (__attribute__((address_space(3))) void*)(lp), 16, 0, 0)

// ---------------- dtype detector: 1 wave, inspects low 16 bits of 64 words ---
__global__ void detect_kernel(const unsigned int* __restrict__ q, int* __restrict__ flag) {
  const int lane = threadIdx.x;
  const unsigned int w = q[lane];
  const unsigned int lo = w & 0xffffu;
  const unsigned int e = (lo >> 7) & 0xffu;
  const bool ok = (lo == 0u) || (e >= 100u && e <= 141u);
  const unsigned long long m = __ballot(ok);
  if (lane == 0) flag[0] = (__popcll(m) == 64) ? 1 : 0;
}

// ---------------- combined 1-D param convert: 9 tensors -> contiguous bf16 ---
__global__ void cvt_params_kernel(const int* __restrict__ flagp,
                                  const void* qkv_b, const void* proj_b,
                                  const void* n1g, const void* n1b,
                                  const void* n2g, const void* n2b,
                                  const void* fc1_b, const void* fc2_b,
                                  const void* rpb, bf16* __restrict__ dst) {
  const int f32 = (flagp[0] == 0);
  int i = blockIdx.x * blockDim.x + threadIdx.x;
  if (i >= 3510) return;
  const void* src; int j = i;
  if      (j < 576)  { src = qkv_b; }
  else if ((j -= 576)  < 192) { src = proj_b; }
  else if ((j -= 192)  < 192) { src = n1g; }
  else if ((j -= 192)  < 192) { src = n1b; }
  else if ((j -= 192)  < 192) { src = n2g; }
  else if ((j -= 192)  < 192) { src = n2b; }
  else if ((j -= 192)  < 768) { src = fc1_b; }
  else if ((j -= 768)  < 192) { src = fc2_b; }
  else { j -= 192; src = rpb; }
  dst[i] = f2bf(loadExt(src, j, f32));
}

// ---------------- fused convert + transpose: src[K,N] (ext) -> dst[N,K] bf16 -
__global__ void cvtT_kernel(const int* __restrict__ flagp, const void* __restrict__ src,
                            bf16* __restrict__ dst, int K, int N) {
  const int f32 = (flagp[0] == 0);
  int i = blockIdx.x * blockDim.x + threadIdx.x;
  if (i >= K * N) return;
  int n = i / K, k = i - n * K;
  dst[i] = f2bf(loadExt(src, (long)k * N + n, f32));
}

// ---------------- rel-pos bias table: btab[head][n*50+m] (padded stride 50) --
__global__ void biastab_kernel(const bf16* __restrict__ rpb,
                               bf16* __restrict__ btab) {
  int i = blockIdx.x * blockDim.x + threadIdx.x;
  if (i >= 6 * 2450) return;
  int head = i / 2450, r = i - head * 2450;
  int n = r / 50, m = r - n * 50;
  float v = 0.f;
  if (n < 49 && m < 49) {
    int r1 = n / 7, c1 = n - 7 * r1, r2 = m / 7, c2 = m - 7 * r2;
    v = bf2f(rpb[((r1 - r2 + 6) * 13 + (c1 - c2 + 6)) * 6 + head]);
  }
  btab[i] = f2bf(v);
}

// ---------------- LayerNorm: one wave per 192-elem row --------------------
__global__ __launch_bounds__(256) void ln_kernel(const int* __restrict__ flagp, int ext,
                                                 const void* __restrict__ x,
                                                 const bf16* __restrict__ g,
                                                 const bf16* __restrict__ b,
                                                 bf16* __restrict__ out) {
  const int f32 = ext && (flagp[0] == 0);
  const long row = (long)blockIdx.x * 4 + (threadIdx.x >> 6);
  const int lane = threadIdx.x & 63;
  const long gbase = row * 192;
  float v0 = loadExt(x, gbase + lane, f32);
  float v1 = loadExt(x, gbase + lane + 64, f32);
  float v2 = loadExt(x, gbase + lane + 128, f32);
  float s = v0 + v1 + v2;
  #pragma unroll
  for (int off = 32; off > 0; off >>= 1) s += __shfl_xor(s, off, 64);
  const float mu = s * (1.0f / 192.0f);
  float d0 = v0 - mu, d1 = v1 - mu, d2 = v2 - mu;
  float vv = d0 * d0 + d1 * d1 + d2 * d2;
  #pragma unroll
  for (int off = 32; off > 0; off >>= 1) vv += __shfl_xor(vv, off, 64);
  const float rstd = rsqrtf(vv * (1.0f / 192.0f) + 1e-5f);
  bf16* orow = out + row * 192;
  orow[lane]       = f2bf(d0 * rstd * bf2f(g[lane])       + bf2f(b[lane]));
  orow[lane + 64]  = f2bf(d1 * rstd * bf2f(g[lane + 64])  + bf2f(b[lane + 64]));
  orow[lane + 128] = f2bf(d2 * rstd * bf2f(g[lane + 128]) + bf2f(b[lane + 128]));
}

// ---------------- bf16 MFMA GEMM: C = A[M,K]*BT[N,K]^T + bias, epilogue -----
// EPI: 0 = bias, 1 = bias+GELU(exact), 2 = bias+residual.
// Pipeline: async global_load_lds (16B) direct-to-LDS, linear layout with
// involutive XOR slot-swizzle (source-side + read-side), prefetch next k-tile
// before computing current, ONE __syncthreads per k-step (its vmcnt(0) drain
// is the pipeline wait). Grid: 1-D, m-major decode + bijective XCD chunking.
// MFMA operands swapped (D[n][m]) so each lane's 4 acc regs are 4 consecutive
// N columns of one row -> vectorized 8/16B stores + residual loads.
template <int EPI>
__global__ __launch_bounds__(256) void gemm_bt(const bf16* __restrict__ A,
                                               const bf16* __restrict__ BT,
                                               const bf16* __restrict__ bias,
                                               const int* __restrict__ flagp,
                                               const void* res, int res_ext,
                                               void* out, int out_ext,
                                               int M, int N, int K) {
  __shared__ __align__(16) bf16 As[2][128 * 32];
  __shared__ __align__(16) bf16 Bs[2][64 * 32];
  const int xf32 = (flagp[0] == 0);
  const int tid = threadIdx.x;
  const int wave = tid >> 6;
  const int lane = tid & 63;
  const int l16 = lane & 15;
  const int quad = lane >> 4;

  // ---- block decode: m-major within XCD-contiguous chunks (gridDim.x%8==0;
  //      identity fallback otherwise so the decode can never go OOB)
  const int nbn = N >> 6;
  const int cpx = gridDim.x >> 3;
  const int wg = (gridDim.x & 7) ? (int)blockIdx.x
                                 : (blockIdx.x & 7) * cpx + (blockIdx.x >> 3);
  const int mb = wg / nbn;
  const int nb = wg - mb * nbn;
  const long m0 = (long)mb * 128;
  const int n0 = nb << 6;

  // ---- staging decode: thread t owns 16B chunk t (and t+256 for A's 2nd half)
  // chunk c -> row r=c>>2, slot s=c&3; source slot swizzled: s ^ ((r>>1)&3)
  const int rS = tid >> 2;
  const int sS = tid & 3;
  const int ss = sS ^ ((rS >> 1) & 3);        // same for row rS+64 (64%8==0)
  const bf16* gA0 = A + (m0 + rS) * (long)K + ss * 8;
  const bf16* gA1 = A + (m0 + rS + 64) * (long)K + ss * 8;
  const bf16* gB  = BT + (long)(n0 + rS) * K + ss * 8;

  floatx4 acc[2][4];
  #pragma unroll
  for (int i = 0; i < 2; i++)
    #pragma unroll
    for (int j = 0; j < 4; j++) acc[i][j] = (floatx4){0.f, 0.f, 0.f, 0.f};

  // fragment-read swizzle: row ra -> slot (quad ^ ((ra>>1)&3)); for all our
  // rows ra = 16k + l16, so (ra>>1)&3 == (l16>>1)&3 (wave/ms/ns terms vanish)
  const int swz = (quad ^ ((l16 >> 1) & 3)) << 3;
  const int arow = wave * 32 + l16;

  // prologue: stage k-tile 0 into buf 0
  GLOAD16(gA0, &As[0][tid * 8]);
  GLOAD16(gA1, &As[0][(tid + 256) * 8]);
  GLOAD16(gB,  &Bs[0][tid * 8]);
  __syncthreads();

  int cur = 0;
  for (int k0 = 0; k0 < K; k0 += 32) {
    if (k0 + 32 < K) {  // issue next tile's loads before computing current
      const int nxt = cur ^ 1;
      GLOAD16(gA0 + k0 + 32, &As[nxt][tid * 8]);
      GLOAD16(gA1 + k0 + 32, &As[nxt][(tid + 256) * 8]);
      GLOAD16(gB  + k0 + 32, &Bs[nxt][tid * 8]);
    }
    bf16x8 af[2], bfr[4];
    #pragma unroll
    for (int ms = 0; ms < 2; ms++)
      af[ms] = *(const bf16x8*)&As[cur][(arow + ms * 16) * 32 + swz];
    #pragma unroll
    for (int ns = 0; ns < 4; ns++)
      bfr[ns] = *(const bf16x8*)&Bs[cur][(ns * 16 + l16) * 32 + swz];
    #pragma unroll
    for (int ms = 0; ms < 2; ms++)
      #pragma unroll
      for (int ns = 0; ns < 4; ns++)
        acc[ms][ns] = __builtin_amdgcn_mfma_f32_16x16x32_bf16(bfr[ns], af[ms], acc[ms][ns], 0, 0, 0);
    __syncthreads();   // drains vmcnt(0): next tile landed; all reads of cur done
    cur ^= 1;
  }

  // ---- epilogue: lane owns rows m = ..+l16, cols n = ..+quad*4 + (0..3)
  #pragma unroll
  for (int ms = 0; ms < 2; ms++) {
    const long row = m0 + wave * 32 + ms * 16 + l16;
    #pragma unroll
    for (int ns = 0; ns < 4; ns++) {
      const int col = n0 + ns * 16 + quad * 4;
      const long idx = row * (long)N + col;
      float v[4];
      #pragma unroll
      for (int r = 0; r < 4; r++) v[r] = acc[ms][ns][r] + bf2f(bias[col + r]);
      if (EPI == 1) {
        #pragma unroll
        for (int r = 0; r < 4; r++)
          v[r] = 0.5f * v[r] * (1.0f + erff(v[r] * 0.70710678118654752f));
      }
      if (EPI == 2) {
        if (res_ext && xf32) {
          const float4 t = *(const float4*)((const float*)res + idx);
          v[0] += t.x; v[1] += t.y; v[2] += t.z; v[3] += t.w;
        } else {
          const bf16x4 t = *(const bf16x4*)((const bf16*)res + idx);
          #pragma unroll
          for (int r = 0; r < 4; r++) v[r] += (float)t[r];
        }
      }
      if (out_ext && xf32) {
        float4 t; t.x = v[0]; t.y = v[1]; t.z = v[2]; t.w = v[3];
        *(float4*)((float*)out + idx) = t;
      } else {
        bf16x4 t;
        #pragma unroll
        for (int r = 0; r < 4; r++) t[r] = (__bf16)v[r];
        *(bf16x4*)((bf16*)out + idx) = t;
      }
    }
  }
}

// ---------------- window attention: one wave per (window, head), full batch -
__global__ __launch_bounds__(64) void attn_kernel(const bf16* __restrict__ qkv,  // [100352,576]
                                                  const bf16* __restrict__ btab, // [6,2450]
                                                  bf16* __restrict__ out) {      // [100352,192]
  __shared__ __align__(16) float ksh[49 * 32];
  __shared__ __align__(16) float vsh[49 * 32];
  __shared__ __align__(4) bf16 bsh[2450];
  __shared__ int rowIdx[49];
  __shared__ int regn[49];
  const int lane = threadIdx.x;
  const int unit = blockIdx.x;          // [0, 12288)
  const int head = unit % 6;
  const int wIdx = unit / 6;            // [0, 2048)
  const int b = wIdx >> 8;
  const int w2 = wIdx & 255;
  const int wh = w2 >> 4;
  const int ww = w2 & 15;

  if (lane < 49) {
    const int r = lane / 7, c = lane - 7 * (lane / 7);
    const int hr = wh * 7 + r;          // rolled-image coords
    const int wr = ww * 7 + c;
    int h = hr + 3; if (h >= 112) h -= 112;
    int w = wr + 3; if (w >= 112) w -= 112;
    rowIdx[lane] = b * 12544 + h * 112 + w;
    const int rh = hr < 105 ? 0 : (hr < 109 ? 1 : 2);
    const int rw = wr < 105 ? 0 : (wr < 109 ? 1 : 2);
    regn[lane] = rh * 3 + rw;
  }
  {
    const unsigned int* bsrc = (const unsigned int*)(btab + head * 2450);
    unsigned int* bdst = (unsigned int*)bsh;
    for (int i = lane; i < 1225; i += 64) bdst[i] = bsrc[i];
  }
  __syncthreads();

  for (int i = lane; i < 196; i += 64) {
    const int r = i >> 2, c = (i & 3) * 8;
    const long base = (long)rowIdx[r] * 576 + head * 32 + c;
    bf16x8 kk = *(const bf16x8*)&qkv[base + 192];
    bf16x8 vv = *(const bf16x8*)&qkv[base + 384];
    #pragma unroll
    for (int j = 0; j < 8; j++) {
      ksh[r * 32 + c + j] = (float)kk[j];
      vsh[r * 32 + c + j] = (float)vv[j];
    }
  }
  __syncthreads();

  if (lane < 49) {
    const float scale = 0.17677669529663687f;  // 1/sqrt(32)
    float qv[32];
    {
      const long qb = (long)rowIdx[lane] * 576 + head * 32;
      #pragma unroll
      for (int c = 0; c < 32; c += 8) {
        bf16x8 qq = *(const bf16x8*)&qkv[qb + c];
        #pragma unroll
        for (int j = 0; j < 8; j++) qv[c + j] = (float)qq[j] * scale;
      }
    }
    const int myreg = regn[lane];
    float s[49];
    #pragma unroll
    for (int m = 0; m < 49; m++) {
      float a = 0.f;
      #pragma unroll
      for (int d = 0; d < 32; d++) a += qv[d] * ksh[m * 32 + d];
      a += bf2f(bsh[lane * 50 + m]);
      if (regn[m] != myreg) a -= 100.0f;
      s[m] = a;
    }
    float mx = s[0];
    #pragma unroll
    for (int m = 1; m < 49; m++) mx = fmaxf(mx, s[m]);
    float sum = 0.f;
    #pragma unroll
    for (int m = 0; m < 49; m++) { s[m] = __expf(s[m] - mx); sum += s[m]; }
    const float inv = 1.0f / sum;
    float o[32];
    #pragma unroll
    for (int d = 0; d < 32; d++) o[d] = 0.f;
    #pragma unroll
    for (int m = 0; m < 49; m++) {
      const float p = s[m] * inv;
      #pragma unroll
      for (int d = 0; d < 32; d++) o[d] += p * vsh[m * 32 + d];
    }
    const long ob = (long)rowIdx[lane] * 192 + head * 32;
    #pragma unroll
    for (int c = 0; c < 32; c += 8) {
      bf16x8 ov;
      #pragma unroll
      for (int j = 0; j < 8; j++) ov[j] = (__bf16)o[c + j];
      *(bf16x8*)&out[ob + c] = ov;
    }
  }
}

// ---------------------------------------------------------------------------
// ws layout (bf16 after 16B flag header), total ~231.7 MB (ws_size ~308 MB):
//   wsA  [100352,192] = 19,267,584   (ln1 out / attn out / ln2 out)
//   wsB  [100352,768] = 77,070,336   (qkv [.,576] then fc1 hidden [.,768])
//   xbuf [100352,192] = 19,267,584   (attention-branch residual x, bf16)
//   qkvT 110592  projT 36864  fc1T 147456  fc2T 147456  params 3510  btab 14700
extern "C" void kernel_launch(void* const* d_in, const int* in_sizes, int n_in,
                              void* d_out, int out_size, void* d_ws, size_t ws_size,
                              hipStream_t stream) {
  const void* query   = d_in[0];
  const void* norm1_g = d_in[1];
  const void* norm1_b = d_in[2];
  const void* qkv_w   = d_in[3];
  const void* qkv_b   = d_in[4];
  const void* rpb     = d_in[5];
  const void* proj_w  = d_in[6];
  const void* proj_b  = d_in[7];
  const void* norm2_g = d_in[8];
  const void* norm2_b = d_in[9];
  const void* fc1_w   = d_in[10];
  const void* fc1_b   = d_in[11];
  const void* fc2_w   = d_in[12];
  const void* fc2_b   = d_in[13];

  const long M = 100352;

  int* flag  = (int*)d_ws;
  bf16* base = (bf16*)((char*)d_ws + 16);
  bf16* wsA   = base;                   // 19,267,584
  bf16* wsB   = wsA + M * 192;          // 77,070,336
  bf16* xbuf  = wsB + M * 768;          // 19,267,584
  bf16* qkvT  = xbuf + M * 192;         // 110,592
  bf16* projT = qkvT + 110592;          // 36,864
  bf16* fc1T  = projT + 36864;          // 147,456
  bf16* fc2T  = fc1T + 147456;          // 147,456
  bf16* pPAR  = fc2T + 147456;          // 3,510
  bf16* pQKVB = pPAR;                   // 576
  bf16* pPRJB = pQKVB + 576;            // 192
  bf16* pN1G  = pPRJB + 192;
  bf16* pN1B  = pN1G + 192;
  bf16* pN2G  = pN1B + 192;
  bf16* pN2B  = pN2G + 192;
  bf16* pFC1B = pN2B + 192;             // 768
  bf16* pFC2B = pFC1B + 768;            // 192
  bf16* pRPB  = pFC2B + 192;            // 1,014
  bf16* btab  = pPAR + 3510;            // 14,700

  detect_kernel<<<1, 64, 0, stream>>>((const unsigned int*)query, flag);
  cvt_params_kernel<<<14, 256, 0, stream>>>(flag, qkv_b, proj_b, norm1_g, norm1_b,
                                            norm2_g, norm2_b, fc1_b, fc2_b, rpb, pPAR);
  cvtT_kernel<<<(192 * 576 + 255) / 256, 256, 0, stream>>>(flag, qkv_w, qkvT, 192, 576);
  cvtT_kernel<<<(192 * 192 + 255) / 256, 256, 0, stream>>>(flag, proj_w, projT, 192, 192);
  cvtT_kernel<<<(192 * 768 + 255) / 256, 256, 0, stream>>>(flag, fc1_w, fc1T, 192, 768);
  cvtT_kernel<<<(768 * 192 + 255) / 256, 256, 0, stream>>>(flag, fc2_w, fc2T, 768, 192);
  biastab_kernel<<<(6 * 2450 + 255) / 256, 256, 0, stream>>>(pRPB, btab);

  // ---- attention branch (full M) ----
  ln_kernel<<<M / 4, 256, 0, stream>>>(flag, 1, query, pN1G, pN1B, wsA);
  gemm_bt<0><<<784 * 9, 256, 0, stream>>>(wsA, qkvT, pQKVB, flag,
                                          nullptr, 0, wsB, 0, (int)M, 576, 192);
  attn_kernel<<<12288, 64, 0, stream>>>(wsB, btab, wsA);
  // x = query + attn @ proj_w + b -> xbuf (bf16 internal)
  gemm_bt<2><<<784 * 3, 256, 0, stream>>>(wsA, projT, pPRJB, flag,
                                          query, 1, xbuf, 0, (int)M, 192, 192);

  // ---- MLP branch (full M) ----
  ln_kernel<<<M / 4, 256, 0, stream>>>(flag, 0, xbuf, pN2G, pN2B, wsA);
  gemm_bt<1><<<784 * 12, 256, 0, stream>>>(flag ? wsA : wsA, fc1T, pFC1B, flag,
                                           nullptr, 0, wsB, 0, (int)M, 768, 192);
  // out = x + h @ fc2 + b -> d_out (external dtype), residual from xbuf (bf16)
  gemm_bt<2><<<784 * 3, 256, 0, stream>>>(wsB, fc2T, pFC2B, flag,
                                          xbuf, 0, d_out, 1, (int)M, 192, 768);
}

// Round 4
// 614.439 us; speedup vs baseline: 1.3806x; 1.0858x over previous
//
#include <hip/hip_runtime.h>
#include <hip/hip_bf16.h>
#include <math.h>

using bf16 = __hip_bfloat16;
typedef __bf16 bf16x8 __attribute__((ext_vector_type(8)));
typedef __bf16 bf16x4 __attribute__((ext_vector_type(4)));
typedef float floatx4 __attribute__((ext_vector_type(4)));

__device__ __forceinline__ float bf2f(bf16 x) { return __bfloat162float(x); }
__device__ __forceinline__ bf16 f2bf(float x) { return __float2bfloat16(x); }

// flag semantics: flagp[0] == 1 -> external tensors are bf16; 0 -> float32.
__device__ __forceinline__ float loadExt(const void* p, long i, int f32) {
  return f32 ? ((const float*)p)[i] : bf2f(((const bf16*)p)[i]);
}
__device__ __forceinline__ void storeExt(void* p, long i, int f32, float v) {
  if (f32) ((float*)p)[i] = v;
  else     ((bf16*)p)[i] = f2bf(v);
}

// async 16B global->LDS copy (gfx950). LDS dest is wave-uniform base + lane*16.
#define GLOAD16(gp, lp)                                                       \
  __builtin_amdgcn_global_load_lds(                                           \
      (const __attribute__((address_space(1))) void*)(gp),                    \
      (__attribute__((address_space(3))) void*)(lp), 16, 0, 0)

// ---------------- dtype detector: 1 wave, inspects low 16 bits of 64 words ---
__global__ void detect_kernel(const unsigned int* __restrict__ q, int* __restrict__ flag) {
  const int lane = threadIdx.x;
  const unsigned int w = q[lane];
  const unsigned int lo = w & 0xffffu;
  const unsigned int e = (lo >> 7) & 0xffu;
  const bool ok = (lo == 0u) || (e >= 100u && e <= 141u);
  const unsigned long long m = __ballot(ok);
  if (lane == 0) flag[0] = (__popcll(m) == 64) ? 1 : 0;
}

// ---------------- combined 1-D param convert: 9 tensors -> contiguous bf16 ---
__global__ void cvt_params_kernel(const int* __restrict__ flagp,
                                  const void* qkv_b, const void* proj_b,
                                  const void* n1g, const void* n1b,
                                  const void* n2g, const void* n2b,
                                  const void* fc1_b, const void* fc2_b,
                                  const void* rpb, bf16* __restrict__ dst) {
  const int f32 = (flagp[0] == 0);
  int i = blockIdx.x * blockDim.x + threadIdx.x;
  if (i >= 3510) return;
  const void* src; int j = i;
  if      (j < 576)  { src = qkv_b; }
  else if ((j -= 576)  < 192) { src = proj_b; }
  else if ((j -= 192)  < 192) { src = n1g; }
  else if ((j -= 192)  < 192) { src = n1b; }
  else if ((j -= 192)  < 192) { src = n2g; }
  else if ((j -= 192)  < 192) { src = n2b; }
  else if ((j -= 192)  < 768) { src = fc1_b; }
  else if ((j -= 768)  < 192) { src = fc2_b; }
  else { j -= 192; src = rpb; }
  dst[i] = f2bf(loadExt(src, j, f32));
}

// ---------------- fused convert + transpose: src[K,N] (ext) -> dst[N,K] bf16 -
__global__ void cvtT_kernel(const int* __restrict__ flagp, const void* __restrict__ src,
                            bf16* __restrict__ dst, int K, int N) {
  const int f32 = (flagp[0] == 0);
  int i = blockIdx.x * blockDim.x + threadIdx.x;
  if (i >= K * N) return;
  int n = i / K, k = i - n * K;
  dst[i] = f2bf(loadExt(src, (long)k * N + n, f32));
}

// ---------------- rel-pos bias table: btab[head][n*50+m] (padded stride 50) --
__global__ void biastab_kernel(const bf16* __restrict__ rpb,
                               bf16* __restrict__ btab) {
  int i = blockIdx.x * blockDim.x + threadIdx.x;
  if (i >= 6 * 2450) return;
  int head = i / 2450, r = i - head * 2450;
  int n = r / 50, m = r - n * 50;
  float v = 0.f;
  if (n < 49 && m < 49) {
    int r1 = n / 7, c1 = n - 7 * r1, r2 = m / 7, c2 = m - 7 * r2;
    v = bf2f(rpb[((r1 - r2 + 6) * 13 + (c1 - c2 + 6)) * 6 + head]);
  }
  btab[i] = f2bf(v);
}

// ---------------- LayerNorm: one wave per 192-elem row --------------------
__global__ __launch_bounds__(256) void ln_kernel(const int* __restrict__ flagp, int ext,
                                                 const void* __restrict__ x,
                                                 const bf16* __restrict__ g,
                                                 const bf16* __restrict__ b,
                                                 bf16* __restrict__ out) {
  const int f32 = ext && (flagp[0] == 0);
  const long row = (long)blockIdx.x * 4 + (threadIdx.x >> 6);
  const int lane = threadIdx.x & 63;
  const long gbase = row * 192;
  float v0 = loadExt(x, gbase + lane, f32);
  float v1 = loadExt(x, gbase + lane + 64, f32);
  float v2 = loadExt(x, gbase + lane + 128, f32);
  float s = v0 + v1 + v2;
  #pragma unroll
  for (int off = 32; off > 0; off >>= 1) s += __shfl_xor(s, off, 64);
  const float mu = s * (1.0f / 192.0f);
  float d0 = v0 - mu, d1 = v1 - mu, d2 = v2 - mu;
  float vv = d0 * d0 + d1 * d1 + d2 * d2;
  #pragma unroll
  for (int off = 32; off > 0; off >>= 1) vv += __shfl_xor(vv, off, 64);
  const float rstd = rsqrtf(vv * (1.0f / 192.0f) + 1e-5f);
  bf16* orow = out + row * 192;
  orow[lane]       = f2bf(d0 * rstd * bf2f(g[lane])       + bf2f(b[lane]));
  orow[lane + 64]  = f2bf(d1 * rstd * bf2f(g[lane + 64])  + bf2f(b[lane + 64]));
  orow[lane + 128] = f2bf(d2 * rstd * bf2f(g[lane + 128]) + bf2f(b[lane + 128]));
}

// ---------------- bf16 MFMA GEMM: C = A[M,K]*BT[N,K]^T + bias, epilogue -----
// EPI: 0 = bias, 1 = bias+GELU(exact), 2 = bias+residual.
template <int EPI>
__global__ __launch_bounds__(256) void gemm_bt(const bf16* __restrict__ A,
                                               const bf16* __restrict__ BT,
                                               const bf16* __restrict__ bias,
                                               const int* __restrict__ flagp,
                                               const void* res, int res_ext,
                                               void* out, int out_ext,
                                               int M, int N, int K) {
  __shared__ __align__(16) bf16 As[2][128 * 32];
  __shared__ __align__(16) bf16 Bs[2][64 * 32];
  const int xf32 = (flagp[0] == 0);
  const int tid = threadIdx.x;
  const int wave = tid >> 6;
  const int lane = tid & 63;
  const int l16 = lane & 15;
  const int quad = lane >> 4;

  // ---- block decode: m-major within XCD-contiguous chunks (gridDim.x%8==0;
  //      identity fallback otherwise so the decode can never go OOB)
  const int nbn = N >> 6;
  const int cpx = gridDim.x >> 3;
  const int wg = (gridDim.x & 7) ? (int)blockIdx.x
                                 : (blockIdx.x & 7) * cpx + (blockIdx.x >> 3);
  const int mb = wg / nbn;
  const int nb = wg - mb * nbn;
  const long m0 = (long)mb * 128;
  const int n0 = nb << 6;

  // ---- staging decode: thread t owns 16B chunk t (and t+256 for A's 2nd half)
  const int rS = tid >> 2;
  const int sS = tid & 3;
  const int ss = sS ^ ((rS >> 1) & 3);        // same for row rS+64 (64%8==0)
  const bf16* gA0 = A + (m0 + rS) * (long)K + ss * 8;
  const bf16* gA1 = A + (m0 + rS + 64) * (long)K + ss * 8;
  const bf16* gB  = BT + (long)(n0 + rS) * K + ss * 8;

  floatx4 acc[2][4];
  #pragma unroll
  for (int i = 0; i < 2; i++)
    #pragma unroll
    for (int j = 0; j < 4; j++) acc[i][j] = (floatx4){0.f, 0.f, 0.f, 0.f};

  const int swz = (quad ^ ((l16 >> 1) & 3)) << 3;
  const int arow = wave * 32 + l16;

  // prologue: stage k-tile 0 into buf 0
  GLOAD16(gA0, &As[0][tid * 8]);
  GLOAD16(gA1, &As[0][(tid + 256) * 8]);
  GLOAD16(gB,  &Bs[0][tid * 8]);
  __syncthreads();

  int cur = 0;
  for (int k0 = 0; k0 < K; k0 += 32) {
    if (k0 + 32 < K) {  // issue next tile's loads before computing current
      const int nxt = cur ^ 1;
      GLOAD16(gA0 + k0 + 32, &As[nxt][tid * 8]);
      GLOAD16(gA1 + k0 + 32, &As[nxt][(tid + 256) * 8]);
      GLOAD16(gB  + k0 + 32, &Bs[nxt][tid * 8]);
    }
    bf16x8 af[2], bfr[4];
    #pragma unroll
    for (int ms = 0; ms < 2; ms++)
      af[ms] = *(const bf16x8*)&As[cur][(arow + ms * 16) * 32 + swz];
    #pragma unroll
    for (int ns = 0; ns < 4; ns++)
      bfr[ns] = *(const bf16x8*)&Bs[cur][(ns * 16 + l16) * 32 + swz];
    #pragma unroll
    for (int ms = 0; ms < 2; ms++)
      #pragma unroll
      for (int ns = 0; ns < 4; ns++)
        acc[ms][ns] = __builtin_amdgcn_mfma_f32_16x16x32_bf16(bfr[ns], af[ms], acc[ms][ns], 0, 0, 0);
    __syncthreads();   // drains vmcnt(0): next tile landed; all reads of cur done
    cur ^= 1;
  }

  // ---- epilogue: lane owns rows m = ..+l16, cols n = ..+quad*4 + (0..3)
  #pragma unroll
  for (int ms = 0; ms < 2; ms++) {
    const long row = m0 + wave * 32 + ms * 16 + l16;
    #pragma unroll
    for (int ns = 0; ns < 4; ns++) {
      const int col = n0 + ns * 16 + quad * 4;
      const long idx = row * (long)N + col;
      float v[4];
      #pragma unroll
      for (int r = 0; r < 4; r++) v[r] = acc[ms][ns][r] + bf2f(bias[col + r]);
      if (EPI == 1) {
        #pragma unroll
        for (int r = 0; r < 4; r++)
          v[r] = 0.5f * v[r] * (1.0f + erff(v[r] * 0.70710678118654752f));
      }
      if (EPI == 2) {
        if (res_ext && xf32) {
          const float4 t = *(const float4*)((const float*)res + idx);
          v[0] += t.x; v[1] += t.y; v[2] += t.z; v[3] += t.w;
        } else {
          const bf16x4 t = *(const bf16x4*)((const bf16*)res + idx);
          #pragma unroll
          for (int r = 0; r < 4; r++) v[r] += (float)t[r];
        }
      }
      if (out_ext && xf32) {
        float4 t; t.x = v[0]; t.y = v[1]; t.z = v[2]; t.w = v[3];
        *(float4*)((float*)out + idx) = t;
      } else {
        bf16x4 t;
        #pragma unroll
        for (int r = 0; r < 4; r++) t[r] = (__bf16)v[r];
        *(bf16x4*)((bf16*)out + idx) = t;
      }
    }
  }
}

// ---------------- MFMA window attention: one wave per (window, head) --------
// Pad 49 -> 64. mfma(X,Y) semantics (verified by gemm_bt): both operands are
// fragments [tile16 + l16][k = quad*8..+7]; D[Xrow on quad*4+r][Yrow on l16].
// QK^T: X=Q-rows, Y=K-rows, both loaded DIRECTLY from global (fragment layout
// == qkv row-gather layout). Softmax in-register (row on one quad's 16 lanes,
// shfl_xor 1/2/4/8 reduce), P normalized in-register, written bf16 to psh.
// PV: X=P-rows (psh), Y=V^T-rows (vshT). Both LDS tiles use XOR slot swizzle
// (slot ^= row&7, 16B slots) -> 2-way conflicts max on b128 reads.
// Pad j>=49 cols of P are exactly 0.0, annihilating dup-row V^T columns.
__global__ __launch_bounds__(64, 3) void attn_kernel(const bf16* __restrict__ qkv,  // [100352,576]
                                                     const bf16* __restrict__ btab, // [6,2450]
                                                     bf16* __restrict__ out) {      // [100352,192]
  __shared__ __align__(16) __bf16 vshT[32 * 64];  // V^T: [d][j], swizzled
  __shared__ __align__(16) __bf16 psh[64 * 64];   // P:   [i][j], swizzled
  __shared__ int rowIdx[64];
  __shared__ int regn[64];
  const int lane = threadIdx.x;
  const int q = lane >> 4, l16 = lane & 15;
  const int unit = blockIdx.x;          // [0, 12288)
  const int head = unit % 6;
  const int wIdx = unit / 6;            // [0, 2048)
  const int b = wIdx >> 8;
  const int w2 = wIdx & 255;
  const int wh = w2 >> 4;
  const int ww = w2 & 15;

  { // phase 0: row gather indices + region ids (pads clamp to row 48)
    const int l = lane < 49 ? lane : 48;
    const int r = l / 7, c = l - 7 * r;
    const int hr = wh * 7 + r;          // rolled-image coords
    const int wr = ww * 7 + c;
    int h = hr + 3; if (h >= 112) h -= 112;
    int w = wr + 3; if (w >= 112) w -= 112;
    rowIdx[lane] = b * 12544 + h * 112 + w;
    const int rh = hr < 105 ? 0 : (hr < 109 ? 1 : 2);
    const int rw = wr < 105 ? 0 : (wr < 109 ? 1 : 2);
    regn[lane] = (lane < 49) ? rh * 3 + rw : 99;
  }
  __syncthreads();

  int ridx[4];
  #pragma unroll
  for (int t = 0; t < 4; t++) ridx[t] = rowIdx[t * 16 + l16];

  // phase 1: stage V^T (swizzled). j=49..63 hold dup-row data; P cols are 0.
  #pragma unroll
  for (int ii = 0; ii < 4; ii++) {
    const int i = lane + ii * 64;       // 0..255
    const int j = i >> 2, c = (i & 3) * 8;
    const bf16x8 vv = *(const bf16x8*)&qkv[(long)rowIdx[j] * 576 + 384 + head * 32 + c];
    #pragma unroll
    for (int jj = 0; jj < 8; jj++) {
      const int d = c + jj;
      vshT[d * 64 + (((j >> 3) ^ (d & 7)) << 3) + (j & 7)] = vv[jj];
    }
  }

  // phase 2: S = Q*K^T via MFMA; Q/K fragments straight from global
  floatx4 s[4][4];
  #pragma unroll
  for (int it = 0; it < 4; it++)
    #pragma unroll
    for (int jt = 0; jt < 4; jt++) s[it][jt] = (floatx4){0.f, 0.f, 0.f, 0.f};
  {
    bf16x8 afq[4], bfk[4];
    #pragma unroll
    for (int t = 0; t < 4; t++) {
      const bf16* pQ = &qkv[(long)ridx[t] * 576 + head * 32 + q * 8];
      afq[t] = *(const bf16x8*)pQ;
      bfk[t] = *(const bf16x8*)(pQ + 192);
    }
    #pragma unroll
    for (int it = 0; it < 4; it++)
      #pragma unroll
      for (int jt = 0; jt < 4; jt++)
        s[it][jt] = __builtin_amdgcn_mfma_f32_16x16x32_bf16(afq[it], bfk[jt], s[it][jt], 0, 0, 0);
  }

  // phase 3: bias + mask + in-register softmax
  int regj[4];
  #pragma unroll
  for (int jt = 0; jt < 4; jt++) regj[jt] = regn[jt * 16 + l16];
  int regi[4][4];
  #pragma unroll
  for (int it = 0; it < 4; it++)
    #pragma unroll
    for (int r = 0; r < 4; r++) regi[it][r] = regn[it * 16 + q * 4 + r];

  const bf16* bt = btab + head * 2450;
  const float scale = 0.17677669529663687f;  // 1/sqrt(32)
  float mrow[4][4];
  #pragma unroll
  for (int it = 0; it < 4; it++)
    #pragma unroll
    for (int r = 0; r < 4; r++) mrow[it][r] = -3e38f;

  #pragma unroll
  for (int it = 0; it < 4; it++)
    #pragma unroll
    for (int jt = 0; jt < 4; jt++)
      #pragma unroll
      for (int r = 0; r < 4; r++) {
        const int i = it * 16 + q * 4 + r;
        const int j = jt * 16 + l16;
        const int bi = (i < 49 ? i : 48) * 50 + (j < 49 ? j : 48);
        float v = s[it][jt][r] * scale + bf2f(bt[bi]);
        if (regi[it][r] != regj[jt]) v -= 100.0f;
        v = (j < 49) ? v : -1e30f;
        s[it][jt][r] = v;
        mrow[it][r] = fmaxf(mrow[it][r], v);
      }
  #pragma unroll
  for (int it = 0; it < 4; it++)
    #pragma unroll
    for (int r = 0; r < 4; r++) {
      float m = mrow[it][r];
      #pragma unroll
      for (int off = 1; off < 16; off <<= 1) m = fmaxf(m, __shfl_xor(m, off, 64));
      mrow[it][r] = m;
    }
  float sum[4][4];
  #pragma unroll
  for (int it = 0; it < 4; it++)
    #pragma unroll
    for (int r = 0; r < 4; r++) sum[it][r] = 0.f;
  #pragma unroll
  for (int it = 0; it < 4; it++)
    #pragma unroll
    for (int jt = 0; jt < 4; jt++)
      #pragma unroll
      for (int r = 0; r < 4; r++) {
        const float e = __expf(s[it][jt][r] - mrow[it][r]);
        s[it][jt][r] = e;
        sum[it][r] += e;
      }
  #pragma unroll
  for (int it = 0; it < 4; it++)
    #pragma unroll
    for (int r = 0; r < 4; r++) {
      float t = sum[it][r];
      #pragma unroll
      for (int off = 1; off < 16; off <<= 1) t += __shfl_xor(t, off, 64);
      mrow[it][r] = 1.0f / t;           // reuse mrow as inv-sum
    }

  // phase 4: write normalized P (bf16, swizzled)
  #pragma unroll
  for (int it = 0; it < 4; it++)
    #pragma unroll
    for (int jt = 0; jt < 4; jt++)
      #pragma unroll
      for (int r = 0; r < 4; r++) {
        const int i = it * 16 + q * 4 + r;
        const int j = jt * 16 + l16;
        psh[i * 64 + (((j >> 3) ^ (i & 7)) << 3) + (j & 7)] =
            (__bf16)(s[it][jt][r] * mrow[it][r]);
      }
  __syncthreads();

  // phase 5: O = P * V  (X = P-rows, Y = V^T-rows; D[i on q*4+r][d on l16])
  floatx4 o[4][2];
  #pragma unroll
  for (int it = 0; it < 4; it++)
    #pragma unroll
    for (int dt = 0; dt < 2; dt++) o[it][dt] = (floatx4){0.f, 0.f, 0.f, 0.f};
  #pragma unroll
  for (int ks = 0; ks < 2; ks++) {
    bf16x8 av[2];
    #pragma unroll
    for (int dt = 0; dt < 2; dt++) {
      const int row = dt * 16 + l16;
      av[dt] = *(const bf16x8*)&vshT[row * 64 + (((ks * 4 + q) ^ (row & 7)) << 3)];
    }
    #pragma unroll
    for (int it = 0; it < 4; it++) {
      const int row = it * 16 + l16;
      const bf16x8 bp = *(const bf16x8*)&psh[row * 64 + (((ks * 4 + q) ^ (row & 7)) << 3)];
      #pragma unroll
      for (int dt = 0; dt < 2; dt++)
        o[it][dt] = __builtin_amdgcn_mfma_f32_16x16x32_bf16(bp, av[dt], o[it][dt], 0, 0, 0);
    }
  }

  // phase 6: store rows i < 49
  #pragma unroll
  for (int it = 0; it < 4; it++)
    #pragma unroll
    for (int r = 0; r < 4; r++) {
      const int i = it * 16 + q * 4 + r;
      if (i < 49) {
        const long ob = (long)rowIdx[i] * 192 + head * 32;
        #pragma unroll
        for (int dt = 0; dt < 2; dt++)
          out[ob + dt * 16 + l16] = f2bf(o[it][dt][r]);
      }
    }
}

// ---------------------------------------------------------------------------
// ws layout (bf16 after 16B flag header), total ~231.7 MB (ws_size ~308 MB):
//   wsA  [100352,192] = 19,267,584   (ln1 out / attn out / ln2 out)
//   wsB  [100352,768] = 77,070,336   (qkv [.,576] then fc1 hidden [.,768])
//   xbuf [100352,192] = 19,267,584   (attention-branch residual x, bf16)
//   qkvT 110592  projT 36864  fc1T 147456  fc2T 147456  params 3510  btab 14700
extern "C" void kernel_launch(void* const* d_in, const int* in_sizes, int n_in,
                              void* d_out, int out_size, void* d_ws, size_t ws_size,
                              hipStream_t stream) {
  const void* query   = d_in[0];
  const void* norm1_g = d_in[1];
  const void* norm1_b = d_in[2];
  const void* qkv_w   = d_in[3];
  const void* qkv_b   = d_in[4];
  const void* rpb     = d_in[5];
  const void* proj_w  = d_in[6];
  const void* proj_b  = d_in[7];
  const void* norm2_g = d_in[8];
  const void* norm2_b = d_in[9];
  const void* fc1_w   = d_in[10];
  const void* fc1_b   = d_in[11];
  const void* fc2_w   = d_in[12];
  const void* fc2_b   = d_in[13];

  const long M = 100352;

  int* flag  = (int*)d_ws;
  bf16* base = (bf16*)((char*)d_ws + 16);
  bf16* wsA   = base;                   // 19,267,584
  bf16* wsB   = wsA + M * 192;          // 77,070,336
  bf16* xbuf  = wsB + M * 768;          // 19,267,584
  bf16* qkvT  = xbuf + M * 192;         // 110,592
  bf16* projT = qkvT + 110592;          // 36,864
  bf16* fc1T  = projT + 36864;          // 147,456
  bf16* fc2T  = fc1T + 147456;          // 147,456
  bf16* pPAR  = fc2T + 147456;          // 3,510
  bf16* pQKVB = pPAR;                   // 576
  bf16* pPRJB = pQKVB + 576;            // 192
  bf16* pN1G  = pPRJB + 192;
  bf16* pN1B  = pN1G + 192;
  bf16* pN2G  = pN1B + 192;
  bf16* pN2B  = pN2G + 192;
  bf16* pFC1B = pN2B + 192;             // 768
  bf16* pFC2B = pFC1B + 768;            // 192
  bf16* pRPB  = pFC2B + 192;            // 1,014
  bf16* btab  = pPAR + 3510;            // 14,700

  detect_kernel<<<1, 64, 0, stream>>>((const unsigned int*)query, flag);
  cvt_params_kernel<<<14, 256, 0, stream>>>(flag, qkv_b, proj_b, norm1_g, norm1_b,
                                            norm2_g, norm2_b, fc1_b, fc2_b, rpb, pPAR);
  cvtT_kernel<<<(192 * 576 + 255) / 256, 256, 0, stream>>>(flag, qkv_w, qkvT, 192, 576);
  cvtT_kernel<<<(192 * 192 + 255) / 256, 256, 0, stream>>>(flag, proj_w, projT, 192, 192);
  cvtT_kernel<<<(192 * 768 + 255) / 256, 256, 0, stream>>>(flag, fc1_w, fc1T, 192, 768);
  cvtT_kernel<<<(768 * 192 + 255) / 256, 256, 0, stream>>>(flag, fc2_w, fc2T, 768, 192);
  biastab_kernel<<<(6 * 2450 + 255) / 256, 256, 0, stream>>>(pRPB, btab);

  // ---- attention branch (full M) ----
  ln_kernel<<<M / 4, 256, 0, stream>>>(flag, 1, query, pN1G, pN1B, wsA);
  gemm_bt<0><<<784 * 9, 256, 0, stream>>>(wsA, qkvT, pQKVB, flag,
                                          nullptr, 0, wsB, 0, (int)M, 576, 192);
  attn_kernel<<<12288, 64, 0, stream>>>(wsB, btab, wsA);
  // x = query + attn @ proj_w + b -> xbuf (bf16 internal)
  gemm_bt<2><<<784 * 3, 256, 0, stream>>>(wsA, projT, pPRJB, flag,
                                          query, 1, xbuf, 0, (int)M, 192, 192);

  // ---- MLP branch (full M) ----
  ln_kernel<<<M / 4, 256, 0, stream>>>(flag, 0, xbuf, pN2G, pN2B, wsA);
  gemm_bt<1><<<784 * 12, 256, 0, stream>>>(wsA, fc1T, pFC1B, flag,
                                           nullptr, 0, wsB, 0, (int)M, 768, 192);
  // out = x + h @ fc2 + b -> d_out (external dtype), residual from xbuf (bf16)
  gemm_bt<2><<<784 * 3, 256, 0, stream>>>(wsB, fc2T, pFC2B, flag,
                                          xbuf, 0, d_out, 1, (int)M, 192, 768);
}